// Round 9
// baseline (425.383 us; speedup 1.0000x reference)
//
#include <hip/hip_runtime.h>

// 2-layer LSTM (H=50) + FC head. Transposed-MFMA fp16, cross-layer pipelined.
// R22 = R21 + INDEPENDENT MFMAs + ADD TREE (isolating the MFMA seam segment):
//   L1: acc = mfma(w0,hb0,0) + mfma(w1,hb1,0)      (2-chain -> 1 + add)
//   L2: acc = (m0+m1)+(m2+m3)                       (4-chain -> 1 + 2 adds)
//   R21 proved the serial seam responds to depth at ~20cy/level (-2 cell
//   levels -> -9us). The dependent-MFMA chain is the ONLY untested seam
//   segment (R14 split it but bundled a +2-level cell that masked it).
//   If dep-MFMA latency ~20-30cy unhidden: L2 sheds ~60-90cy, L1 ~20cy,
//   cost 2-3 add levels (~4cy each). If MFMA latency is absorbed by
//   cross-wave co-issue: neutral. Either way the seam map completes.
// R21 (kept, -9us): scaled cell state C = 2log2e*c kills the pre-exp2 mul;
//   h = fma(-2oo, rt, oo) fuses the tail. Depth 10, 10 trans.
// Session map (falsified): R14 issue-cut/depth+2: +9us. R15 2 blocks/CU 2x
//   work: +300us. R16 8 waves: +50us. R17 -21% LDS reads: 0. R18 flag sync:
//   +75us. R19 split blocks + global ring: +11.5ms.
// Work-conservation: VALU+trans issue ~930 cy/SIMD/phase invariant; phase =
//   issue-envelope + serial seam; seam = read + MFMA + cell(depth) + write +
//   skew; cell depth verified binding at ~20cy/level (R21).
// R13 core: gates^T = W @ h^T; weights in regs (gate rows pre-scaled:
// i/f/o by -log2e, g by +2log2e, incl. bias + x K-lanes), h in LDS frag
// layout; gate rows permuted p=4j+g -> one lane owns a unit's 4 gates;
// x + biases ride dead K-lanes (h1 k=50: x, k=51: 1.0);
// phase p = L1[p] + L2[p-1], ONE barrier/phase (513 = minimum).
// Wave roles: 0..9 dual (prio 1), 10..12 L1 single (12 feeds x), 13..15 L2.

#define HID 50
#define SEQ 512
#define NB 16
#define NTHREADS 1024
#define XP 516            // xs row stride (floats)

typedef _Float16 f16x8 __attribute__((ext_vector_type(8)));
typedef float    f32x4 __attribute__((ext_vector_type(4)));

#define LOG2E 1.44269504f

// pre-scaled activations: input is already  -x*log2e  (sig) or  2x*log2e (tanh)
__device__ __forceinline__ float sig_pre(float y) {
    return __builtin_amdgcn_rcpf(1.0f + __builtin_amdgcn_exp2f(y));
}

// C = 2log2e * c  (scaled cell state). Depth-10 cell, 10 trans (R21).
__device__ __forceinline__ float lstm_cell(const f32x4 g, float& C) {
    const float ii = sig_pre(g[0]);
    const float ff = sig_pre(g[1]);
    const float r2 = __builtin_amdgcn_rcpf(
        1.0f + __builtin_amdgcn_exp2f(g[2]));
    const float gg2 = __builtin_fmaf(-4.0f * LOG2E, r2,
                                     2.0f * LOG2E);      // 2log2e*tanh
    const float oo = sig_pre(g[3]);
    C = __builtin_fmaf(ff, C, ii * gg2);
    const float rt = __builtin_amdgcn_rcpf(
        1.0f + __builtin_amdgcn_exp2f(C));
    return __builtin_fmaf(-2.0f * oo, rt, oo);
}

// h LDS layout: 16B chunk (kt*4+qh)*16 + m holds h[m][k = kt*32+qh*8+0..7].
// Reader (lane m=l15, quad qq, k-chunk kt) reads chunk (kt*4+qq)*16+m.
// Writer of h[m][j]: chunk ((j>>5)*4+((j>>3)&3))*16 + m, half j&7.
// j=50 -> chunk 96+m half 2 (x rides here), j=51 -> chunk 96+m half 3 (1.0).

__global__ __launch_bounds__(NTHREADS)
void lstm2_fc_v22(const float* __restrict__ x,
                  const float* __restrict__ w_ih0,
                  const float* __restrict__ w_hh0,
                  const float* __restrict__ b_ih0,
                  const float* __restrict__ b_hh0,
                  const float* __restrict__ w_ih1,
                  const float* __restrict__ w_hh1,
                  const float* __restrict__ b_ih1,
                  const float* __restrict__ b_hh1,
                  const float* __restrict__ fc_w,
                  const float* __restrict__ fc_b,
                  float* __restrict__ out)
{
    __shared__ float xs[NB * XP];        // 33 KB  x for all 512 steps
    __shared__ f16x8 h1f[2][128];        //  4 KB  h1 double-buffered, frag layout
    __shared__ f16x8 h2f[2][128];        //  4 KB  h2 double-buffered

    const int tid = threadIdx.x;
    const int b0  = blockIdx.x * NB;
    const int w   = tid >> 6;            // wave id 0..15
    const int l15 = tid & 15;            // MFMA lane column (batch m)
    const int qq  = (tid >> 4) & 3;      // MFMA lane quad

    // ---- role assignment (wave-uniform) ----
    const bool dual  = (w <= 9);
    const bool hasL1 = (w <= 12);
    const bool hasL2 = dual || (w >= 13);
    const int  tL1   = w;                        // L1 tile (if hasL1)
    const int  tL2   = dual ? w : (w - 3);       // L2 tile (if hasL2)

    if (dual) __builtin_amdgcn_s_setprio(1);     // pacers issue first post-barrier

    // ---- stage x into LDS (coalesced float4) ----
    for (int idx = tid; idx < NB * 128; idx += NTHREADS) {
        const int b  = idx >> 7;
        const int t4 = idx & 127;
        *(float4*)&xs[b * XP + t4 * 4] =
            *(const float4*)&x[(size_t)(b0 + b) * SEQ + t4 * 4];
    }
    if (tid < NB) {                       // zero x pad column t=512..515
        const float4 z = {0.f, 0.f, 0.f, 0.f};
        *(float4*)&xs[tid * XP + 512] = z;
    }
    // ---- zero h buffers ----
    if (tid < 256) {
        f16x8 z = {};
        h1f[tid >> 7][tid & 127] = z;
        h2f[tid >> 7][tid & 127] = z;
    }

    // ---- load weight A-fragments (one-time), gate rows permuted + SCALED ----
    // lane holds W[p = T*16 + l15][k = kt*32 + qq*8 + j], n(p)=(p&3)*HID+(p>>2)
    // row scale: gate (p&3)==2 (tanh) -> +2log2e, else (sigmoid) -> -log2e.
    // L1 frag (w_hh0): specials k=50 -> w_ih0, k=51 -> biasL1 (both scaled).
    // L2 frags: w_ih1 (special k=51 -> biasL2, scaled) and w_hh1.
    f16x8 wH0[2], wI1[2], wH1[2];
    {
        const int  p1  = tL1 * 16 + l15;
        const bool ok1 = hasL1 && (p1 < 4 * HID);
        const int  n1  = ok1 ? ((p1 & 3) * HID + (p1 >> 2)) : 0;
        const float s1 = ((p1 & 3) == 2) ? (2.0f * LOG2E) : -LOG2E;
        const int  p2  = tL2 * 16 + l15;
        const bool ok2 = hasL2 && (p2 < 4 * HID);
        const int  n2  = ok2 ? ((p2 & 3) * HID + (p2 >> 2)) : 0;
        const float s2 = ((p2 & 3) == 2) ? (2.0f * LOG2E) : -LOG2E;
#pragma unroll
        for (int kt = 0; kt < 2; ++kt) {
            f16x8 f0, f1, f2;
#pragma unroll
            for (int j = 0; j < 8; ++j) {
                const int k = kt * 32 + qq * 8 + j;
                float v0 = 0.0f, v1 = 0.0f, v2 = 0.0f;
                if (ok1) {
                    if (k < HID)          v0 = w_hh0[n1 * HID + k];
                    else if (k == HID)    v0 = w_ih0[n1];
                    else if (k == HID+1)  v0 = b_ih0[n1] + b_hh0[n1];
                    v0 *= s1;
                }
                if (ok2) {
                    if (k < HID)        { v1 = w_ih1[n2 * HID + k];
                                          v2 = w_hh1[n2 * HID + k]; }
                    else if (k == HID+1)  v1 = b_ih1[n2] + b_hh1[n2];
                    v1 *= s2;
                    v2 *= s2;
                }
                f0[j] = (_Float16)v0;
                f1[j] = (_Float16)v1;
                f2[j] = (_Float16)v2;
            }
            wH0[kt] = f0;
            wI1[kt] = f1;
            wH1[kt] = f2;
        }
    }

    // ---- per-lane invariants ----
    const int juL1   = tL1 * 4 + qq;             // unit of my L1 tile (<=51)
    const int juL2   = tL2 * 4 + qq;
    const int wOffL1 = ((((juL1 >> 5) * 4) + ((juL1 >> 3) & 3)) * 16 + l15) * 8 + (juL1 & 7);
    const int wOffL2 = ((((juL2 >> 5) * 4) + ((juL2 >> 3) & 3)) * 16 + l15) * 8 + (juL2 & 7);
    const int rdo = qq * 16 + l15;               // B-frag chunk index, kt=0
    const float* xrow = xs + l15 * XP;           // x row (wave 12, qq==2 feeds x)
    const f32x4 z4 = {0.f, 0.f, 0.f, 0.f};       // hoisted zero accumulator

    float c1 = 0.f, c2 = 0.f;                    // SCALED states (C = 2log2e*c)

    __syncthreads();   // xs + zeros visible

    // ---- seed specials: h1f[0] k=50 = x[m][0]; k=51 = 1.0 in BOTH buffers.
    // The 1.0 lane (wave 12 qq=3) never writes in-loop, so both stay valid.
    if (tid < NB) {
        _Float16* e0 = (_Float16*)&h1f[0][96 + tid];
        e0[2] = (_Float16)xs[tid * XP];
        e0[3] = (_Float16)1.0f;
        ((_Float16*)&h1f[1][96 + tid])[3] = (_Float16)1.0f;
    }
    __syncthreads();

    // ---- phase body: L1-part [p], L2-part [p-1]; one barrier ----
    auto phase = [&](const f16x8* __restrict__ h1o, const f16x8* __restrict__ h2o,
                     f16x8* __restrict__ h1n, f16x8* __restrict__ h2n,
                     int p, bool doL1, bool doL2) {
        const f16x8 hb0 = h1o[rdo];              // shared by L1 and L2 parts
        const f16x8 hb1 = h1o[64 + rdo];
        if (hasL2 && doL2) {
            const f16x8 sb0 = h2o[rdo];
            const f16x8 sb1 = h2o[64 + rdo];
            // 4 INDEPENDENT MFMAs + 2-level add tree (R22)
            const f32x4 m0 = __builtin_amdgcn_mfma_f32_16x16x32_f16(wI1[0], hb0, z4, 0, 0, 0);
            const f32x4 m1 = __builtin_amdgcn_mfma_f32_16x16x32_f16(wI1[1], hb1, z4, 0, 0, 0);
            const f32x4 m2 = __builtin_amdgcn_mfma_f32_16x16x32_f16(wH1[0], sb0, z4, 0, 0, 0);
            const f32x4 m3 = __builtin_amdgcn_mfma_f32_16x16x32_f16(wH1[1], sb1, z4, 0, 0, 0);
            const f32x4 acc = (m0 + m1) + (m2 + m3);
            ((_Float16*)h2n)[wOffL2] = (_Float16)lstm_cell(acc, c2);
        }
        if (hasL1 && doL1) {
            // 2 INDEPENDENT MFMAs + add (R22)
            const f32x4 a0 = __builtin_amdgcn_mfma_f32_16x16x32_f16(wH0[0], hb0, z4, 0, 0, 0);
            const f32x4 a1 = __builtin_amdgcn_mfma_f32_16x16x32_f16(wH0[1], hb1, z4, 0, 0, 0);
            const f32x4 acc = a0 + a1;
            const _Float16 hw = (_Float16)lstm_cell(acc, c1);
            if (w < 12) {                          // wave-uniform
                ((_Float16*)h1n)[wOffL1] = hw;
            } else {                               // wave 12: units 48..51
                if (qq < 2)       ((_Float16*)h1n)[wOffL1] = hw;
                else if (qq == 2) ((_Float16*)h1n)[wOffL1] =
                                      (_Float16)xrow[p + 1];
                /* qq == 3: the 1.0 lane, pre-seeded, never written */
            }
        }
        __syncthreads();
    };

    // phase p reads buf[p&1], writes buf[1-(p&1)]
    phase(h1f[0], h2f[0], h1f[1], h2f[1], 0, true, false);      // L1[0]
#pragma unroll 1
    for (int p = 1; p <= 509; p += 2) {
        phase(h1f[1], h2f[1], h1f[0], h2f[0], p,     true, true);
        phase(h1f[0], h2f[0], h1f[1], h2f[1], p + 1, true, true);
    }
    phase(h1f[1], h2f[1], h1f[0], h2f[0], 511, true,  true);
    phase(h1f[0], h2f[0], h1f[1], h2f[1], 512, false, true);    // L2[511]
    // h2[511] now lives in h2f[1]

    // ============ FC head: out[b] = h2[T-1] . fc_w + fc_b ============
    if (tid < NB) {
        const int m = tid;
        const _Float16* h2e = (const _Float16*)h2f[1];
        float s = fc_b[0];
        for (int j = 0; j < HID; ++j) {
            const int chunk = (((j >> 5) * 4) + ((j >> 3) & 3)) * 16 + m;
            s += fc_w[j] * (float)h2e[chunk * 8 + (j & 7)];
        }
        out[b0 + m] = s;
    }
}

extern "C" void kernel_launch(void* const* d_in, const int* in_sizes, int n_in,
                              void* d_out, int out_size, void* d_ws, size_t ws_size,
                              hipStream_t stream) {
    const float* x     = (const float*)d_in[0];
    const float* w_ih0 = (const float*)d_in[1];
    const float* w_hh0 = (const float*)d_in[2];
    const float* b_ih0 = (const float*)d_in[3];
    const float* b_hh0 = (const float*)d_in[4];
    const float* w_ih1 = (const float*)d_in[5];
    const float* w_hh1 = (const float*)d_in[6];
    const float* b_ih1 = (const float*)d_in[7];
    const float* b_hh1 = (const float*)d_in[8];
    const float* fc_w  = (const float*)d_in[9];
    const float* fc_b  = (const float*)d_in[10];
    float* out = (float*)d_out;

    const int B = in_sizes[0] / SEQ;  // 4096

    lstm2_fc_v22<<<B / NB, NTHREADS, 0, stream>>>(
        x, w_ih0, w_hh0, b_ih0, b_hh0, w_ih1, w_hh1, b_ih1, b_hh1, fc_w, fc_b, out);
}

// Round 10
// 384.150 us; speedup vs baseline: 1.1073x; 1.1073x over previous
//
#include <hip/hip_runtime.h>

// 2-layer LSTM (H=50) + FC head. Transposed-MFMA fp16, cross-layer pipelined.
// R23 = REVERT to R21 (measured best: 352-356 us rocprof / 384 us harness).
// R22 (independent MFMAs + VALU add tree): 405 us, -53. Dependent MFMA
//   chains forward C inside the matrix pipe (cheap); breaking them forces
//   MFMA->VALU hazard drains + 12 v_add/task on the busiest pipe. CHAINED
//   ACCUMULATION IS CORRECT ON CDNA4.
// Session ledger (9 rounds): issue cuts (R14,R17) neutral -- non-binding.
//   TLP reshapes (R15 2blk/2x: +300us; R16 8-wave: +50us) worse. Sync
//   restructure (R18 flags: +75us; R19 split+ring: +11.5ms) worse. MFMA
//   de-chain (R22): +53us. Depth cut (R21): ~0..-5us (noise-level, right
//   sign). Cross-round noise +/-4-7us (R20==R13 code measured 361 vs 354).
// Floor arithmetic: phase = 1650 cy = issue envelope (~930 cy/SIMD, proven
//   non-binding) overlapped with a serial seam (barrier-skew + LDS round
//   trip + chained MFMA + 10-level cell) that survived every decomposition.
//   512 serial steps x ~700 cy pure-latency bound ~= 150 us; the delta is
//   locked inside the one-barrier-per-step recurrence; both sync
//   restructures lost more than the convoy costs.
// R21 cell: scaled state C = 2log2e*c (kills pre-exp2 mul); h = fma(-2oo,
//   rt, oo) (fuses tail). Depth 10, 10 trans, graceful saturation.
// R13 core: gates^T = W @ h^T; weights in regs (gate rows pre-scaled:
// i/f/o by -log2e, g by +2log2e, incl. bias + x K-lanes), h in LDS frag
// layout; gate rows permuted p=4j+g -> one lane owns a unit's 4 gates;
// x + biases ride dead K-lanes (h1 k=50: x, k=51: 1.0);
// phase p = L1[p] + L2[p-1], ONE barrier/phase (513 = minimum).
// Wave roles: 0..9 dual (prio 1), 10..12 L1 single (12 feeds x), 13..15 L2.

#define HID 50
#define SEQ 512
#define NB 16
#define NTHREADS 1024
#define XP 516            // xs row stride (floats)

typedef _Float16 f16x8 __attribute__((ext_vector_type(8)));
typedef float    f32x4 __attribute__((ext_vector_type(4)));

#define LOG2E 1.44269504f

// pre-scaled activations: input is already  -x*log2e  (sig) or  2x*log2e (tanh)
__device__ __forceinline__ float sig_pre(float y) {
    return __builtin_amdgcn_rcpf(1.0f + __builtin_amdgcn_exp2f(y));
}

// C = 2log2e * c  (scaled cell state). Depth-10 cell, 10 trans (R21).
__device__ __forceinline__ float lstm_cell(const f32x4 g, float& C) {
    const float ii = sig_pre(g[0]);
    const float ff = sig_pre(g[1]);
    const float r2 = __builtin_amdgcn_rcpf(
        1.0f + __builtin_amdgcn_exp2f(g[2]));
    const float gg2 = __builtin_fmaf(-4.0f * LOG2E, r2,
                                     2.0f * LOG2E);      // 2log2e*tanh
    const float oo = sig_pre(g[3]);
    C = __builtin_fmaf(ff, C, ii * gg2);
    const float rt = __builtin_amdgcn_rcpf(
        1.0f + __builtin_amdgcn_exp2f(C));
    return __builtin_fmaf(-2.0f * oo, rt, oo);
}

// h LDS layout: 16B chunk (kt*4+qh)*16 + m holds h[m][k = kt*32+qh*8+0..7].
// Reader (lane m=l15, quad qq, k-chunk kt) reads chunk (kt*4+qq)*16+m.
// Writer of h[m][j]: chunk ((j>>5)*4+((j>>3)&3))*16 + m, half j&7.
// j=50 -> chunk 96+m half 2 (x rides here), j=51 -> chunk 96+m half 3 (1.0).

__global__ __launch_bounds__(NTHREADS)
void lstm2_fc_v23(const float* __restrict__ x,
                  const float* __restrict__ w_ih0,
                  const float* __restrict__ w_hh0,
                  const float* __restrict__ b_ih0,
                  const float* __restrict__ b_hh0,
                  const float* __restrict__ w_ih1,
                  const float* __restrict__ w_hh1,
                  const float* __restrict__ b_ih1,
                  const float* __restrict__ b_hh1,
                  const float* __restrict__ fc_w,
                  const float* __restrict__ fc_b,
                  float* __restrict__ out)
{
    __shared__ float xs[NB * XP];        // 33 KB  x for all 512 steps
    __shared__ f16x8 h1f[2][128];        //  4 KB  h1 double-buffered, frag layout
    __shared__ f16x8 h2f[2][128];        //  4 KB  h2 double-buffered

    const int tid = threadIdx.x;
    const int b0  = blockIdx.x * NB;
    const int w   = tid >> 6;            // wave id 0..15
    const int l15 = tid & 15;            // MFMA lane column (batch m)
    const int qq  = (tid >> 4) & 3;      // MFMA lane quad

    // ---- role assignment (wave-uniform) ----
    const bool dual  = (w <= 9);
    const bool hasL1 = (w <= 12);
    const bool hasL2 = dual || (w >= 13);
    const int  tL1   = w;                        // L1 tile (if hasL1)
    const int  tL2   = dual ? w : (w - 3);       // L2 tile (if hasL2)

    if (dual) __builtin_amdgcn_s_setprio(1);     // pacers issue first post-barrier

    // ---- stage x into LDS (coalesced float4) ----
    for (int idx = tid; idx < NB * 128; idx += NTHREADS) {
        const int b  = idx >> 7;
        const int t4 = idx & 127;
        *(float4*)&xs[b * XP + t4 * 4] =
            *(const float4*)&x[(size_t)(b0 + b) * SEQ + t4 * 4];
    }
    if (tid < NB) {                       // zero x pad column t=512..515
        const float4 z = {0.f, 0.f, 0.f, 0.f};
        *(float4*)&xs[tid * XP + 512] = z;
    }
    // ---- zero h buffers ----
    if (tid < 256) {
        f16x8 z = {};
        h1f[tid >> 7][tid & 127] = z;
        h2f[tid >> 7][tid & 127] = z;
    }

    // ---- load weight A-fragments (one-time), gate rows permuted + SCALED ----
    // lane holds W[p = T*16 + l15][k = kt*32 + qq*8 + j], n(p)=(p&3)*HID+(p>>2)
    // row scale: gate (p&3)==2 (tanh) -> +2log2e, else (sigmoid) -> -log2e.
    // L1 frag (w_hh0): specials k=50 -> w_ih0, k=51 -> biasL1 (both scaled).
    // L2 frags: w_ih1 (special k=51 -> biasL2, scaled) and w_hh1.
    f16x8 wH0[2], wI1[2], wH1[2];
    {
        const int  p1  = tL1 * 16 + l15;
        const bool ok1 = hasL1 && (p1 < 4 * HID);
        const int  n1  = ok1 ? ((p1 & 3) * HID + (p1 >> 2)) : 0;
        const float s1 = ((p1 & 3) == 2) ? (2.0f * LOG2E) : -LOG2E;
        const int  p2  = tL2 * 16 + l15;
        const bool ok2 = hasL2 && (p2 < 4 * HID);
        const int  n2  = ok2 ? ((p2 & 3) * HID + (p2 >> 2)) : 0;
        const float s2 = ((p2 & 3) == 2) ? (2.0f * LOG2E) : -LOG2E;
#pragma unroll
        for (int kt = 0; kt < 2; ++kt) {
            f16x8 f0, f1, f2;
#pragma unroll
            for (int j = 0; j < 8; ++j) {
                const int k = kt * 32 + qq * 8 + j;
                float v0 = 0.0f, v1 = 0.0f, v2 = 0.0f;
                if (ok1) {
                    if (k < HID)          v0 = w_hh0[n1 * HID + k];
                    else if (k == HID)    v0 = w_ih0[n1];
                    else if (k == HID+1)  v0 = b_ih0[n1] + b_hh0[n1];
                    v0 *= s1;
                }
                if (ok2) {
                    if (k < HID)        { v1 = w_ih1[n2 * HID + k];
                                          v2 = w_hh1[n2 * HID + k]; }
                    else if (k == HID+1)  v1 = b_ih1[n2] + b_hh1[n2];
                    v1 *= s2;
                    v2 *= s2;
                }
                f0[j] = (_Float16)v0;
                f1[j] = (_Float16)v1;
                f2[j] = (_Float16)v2;
            }
            wH0[kt] = f0;
            wI1[kt] = f1;
            wH1[kt] = f2;
        }
    }

    // ---- per-lane invariants ----
    const int juL1   = tL1 * 4 + qq;             // unit of my L1 tile (<=51)
    const int juL2   = tL2 * 4 + qq;
    const int wOffL1 = ((((juL1 >> 5) * 4) + ((juL1 >> 3) & 3)) * 16 + l15) * 8 + (juL1 & 7);
    const int wOffL2 = ((((juL2 >> 5) * 4) + ((juL2 >> 3) & 3)) * 16 + l15) * 8 + (juL2 & 7);
    const int rdo = qq * 16 + l15;               // B-frag chunk index, kt=0
    const float* xrow = xs + l15 * XP;           // x row (wave 12, qq==2 feeds x)
    const f32x4 z4 = {0.f, 0.f, 0.f, 0.f};       // hoisted zero accumulator

    float c1 = 0.f, c2 = 0.f;                    // SCALED states (C = 2log2e*c)

    __syncthreads();   // xs + zeros visible

    // ---- seed specials: h1f[0] k=50 = x[m][0]; k=51 = 1.0 in BOTH buffers.
    // The 1.0 lane (wave 12 qq=3) never writes in-loop, so both stay valid.
    if (tid < NB) {
        _Float16* e0 = (_Float16*)&h1f[0][96 + tid];
        e0[2] = (_Float16)xs[tid * XP];
        e0[3] = (_Float16)1.0f;
        ((_Float16*)&h1f[1][96 + tid])[3] = (_Float16)1.0f;
    }
    __syncthreads();

    // ---- phase body: L1-part [p], L2-part [p-1]; one barrier ----
    auto phase = [&](const f16x8* __restrict__ h1o, const f16x8* __restrict__ h2o,
                     f16x8* __restrict__ h1n, f16x8* __restrict__ h2n,
                     int p, bool doL1, bool doL2) {
        const f16x8 hb0 = h1o[rdo];              // shared by L1 and L2 parts
        const f16x8 hb1 = h1o[64 + rdo];
        if (hasL2 && doL2) {
            const f16x8 sb0 = h2o[rdo];
            const f16x8 sb1 = h2o[64 + rdo];
            f32x4 acc;
            acc = __builtin_amdgcn_mfma_f32_16x16x32_f16(wI1[0], hb0, z4,  0, 0, 0);
            acc = __builtin_amdgcn_mfma_f32_16x16x32_f16(wI1[1], hb1, acc, 0, 0, 0);
            acc = __builtin_amdgcn_mfma_f32_16x16x32_f16(wH1[0], sb0, acc, 0, 0, 0);
            acc = __builtin_amdgcn_mfma_f32_16x16x32_f16(wH1[1], sb1, acc, 0, 0, 0);
            ((_Float16*)h2n)[wOffL2] = (_Float16)lstm_cell(acc, c2);
        }
        if (hasL1 && doL1) {
            f32x4 acc;
            acc = __builtin_amdgcn_mfma_f32_16x16x32_f16(wH0[0], hb0, z4,  0, 0, 0);
            acc = __builtin_amdgcn_mfma_f32_16x16x32_f16(wH0[1], hb1, acc, 0, 0, 0);
            const _Float16 hw = (_Float16)lstm_cell(acc, c1);
            if (w < 12) {                          // wave-uniform
                ((_Float16*)h1n)[wOffL1] = hw;
            } else {                               // wave 12: units 48..51
                if (qq < 2)       ((_Float16*)h1n)[wOffL1] = hw;
                else if (qq == 2) ((_Float16*)h1n)[wOffL1] =
                                      (_Float16)xrow[p + 1];
                /* qq == 3: the 1.0 lane, pre-seeded, never written */
            }
        }
        __syncthreads();
    };

    // phase p reads buf[p&1], writes buf[1-(p&1)]
    phase(h1f[0], h2f[0], h1f[1], h2f[1], 0, true, false);      // L1[0]
#pragma unroll 1
    for (int p = 1; p <= 509; p += 2) {
        phase(h1f[1], h2f[1], h1f[0], h2f[0], p,     true, true);
        phase(h1f[0], h2f[0], h1f[1], h2f[1], p + 1, true, true);
    }
    phase(h1f[1], h2f[1], h1f[0], h2f[0], 511, true,  true);
    phase(h1f[0], h2f[0], h1f[1], h2f[1], 512, false, true);    // L2[511]
    // h2[511] now lives in h2f[1]

    // ============ FC head: out[b] = h2[T-1] . fc_w + fc_b ============
    if (tid < NB) {
        const int m = tid;
        const _Float16* h2e = (const _Float16*)h2f[1];
        float s = fc_b[0];
        for (int j = 0; j < HID; ++j) {
            const int chunk = (((j >> 5) * 4) + ((j >> 3) & 3)) * 16 + m;
            s += fc_w[j] * (float)h2e[chunk * 8 + (j & 7)];
        }
        out[b0 + m] = s;
    }
}

extern "C" void kernel_launch(void* const* d_in, const int* in_sizes, int n_in,
                              void* d_out, int out_size, void* d_ws, size_t ws_size,
                              hipStream_t stream) {
    const float* x     = (const float*)d_in[0];
    const float* w_ih0 = (const float*)d_in[1];
    const float* w_hh0 = (const float*)d_in[2];
    const float* b_ih0 = (const float*)d_in[3];
    const float* b_hh0 = (const float*)d_in[4];
    const float* w_ih1 = (const float*)d_in[5];
    const float* w_hh1 = (const float*)d_in[6];
    const float* b_ih1 = (const float*)d_in[7];
    const float* b_hh1 = (const float*)d_in[8];
    const float* fc_w  = (const float*)d_in[9];
    const float* fc_b  = (const float*)d_in[10];
    float* out = (float*)d_out;

    const int B = in_sizes[0] / SEQ;  // 4096

    lstm2_fc_v23<<<B / NB, NTHREADS, 0, stream>>>(
        x, w_ih0, w_hh0, b_ih0, b_hh0, w_ih1, w_hh1, b_ih1, b_hh1, fc_w, fc_b, out);
}